// Round 3
// baseline (196.738 us; speedup 1.0000x reference)
//
#include <hip/hip_runtime.h>

// Register-resident fused-16 Jacobi, v6: single dispatch, tile 128x128.
//  - v5 proved the column-per-lane / strip-per-wave structure (56us/dispatch,
//    0 conflicts) but split 16 iters over 2 dispatches: ws round-trip 67MB +
//    kappa/f fetched twice (+67MB) + an extra launch. v6 fuses all 16 steps.
//  - block = 1024 thr = 16 waves; tile 128x128, halo 16, output 96x96
//    (same 1.78x halo ratio as v5). No ws buffer at all.
//  - lane owns 2 adjacent cols (c0=X0+2l, c1=c0+1): W/E between own cols is a
//    register; cross-lane W/E via DPP lane+-1 (2 DPP per row-pair).
//  - kappa staged as two scalar streams at cols c0+1/c0+2 (odd base) so the
//    DPP-garbage weights land EXACTLY at tile cols 0 and 127 -> discard-halo
//    tight: pollution reaches cols 15/112 only after step 16; output [16,112).
//    (An even-aligned float2 kappa load would corrupt col 126 -> output 111.)
//  - N/S: in-register inside an 8-row strip; strip boundary rows cross waves
//    via dbuf LDS (2x2x1024 float2 = 32KB), lane-linear, ONE barrier/step.
//  - weights explicit (wN,wS,wW,wE,Fc per point, zeroed outside domain via
//    cndmask so OOB points stay 0 = GD pad). Persistent state 96 floats/lane.

namespace {
constexpr int    G    = 1024, Ni = 1022;
constexpr int    TOUT = 96, HALO = 16;          // tile 128
constexpr size_t IMG_K = (size_t)G * G;
constexpr size_t IMG_P = (size_t)Ni * Ni;
constexpr float  H2 = (float)(1.0 / (1023.0 * 1023.0));
}

__device__ __forceinline__ float frcp(float x) { return __builtin_amdgcn_rcpf(x); }

// lane l <- lane l-1 (wave_shr1); shifted-in lane gets 0 (bound_ctrl)
__device__ __forceinline__ float lane_shr1(float x) {
    return __builtin_bit_cast(float,
        __builtin_amdgcn_update_dpp(0, __builtin_bit_cast(int, x), 0x138, 0xF, 0xF, true));
}
// lane l <- lane l+1 (wave_shl1)
__device__ __forceinline__ float lane_shl1(float x) {
    return __builtin_bit_cast(float,
        __builtin_amdgcn_update_dpp(0, __builtin_bit_cast(int, x), 0x130, 0xF, 0xF, true));
}

__global__ __launch_bounds__(1024, 4)
void jac_fused16(const float* __restrict__ pre, float* __restrict__ out,
                 const float* __restrict__ kap, const float* __restrict__ fin)
{
    __shared__ float2 ex[2][2][1024];            // [buf][top/bot][tid] = 32 KB

    const int tid = threadIdx.x;
    const int w = tid >> 6, l = tid & 63;        // wave id (0..15), lane id
    const int bx = blockIdx.x, by = blockIdx.y, b = blockIdx.z;
    const int X0 = bx * TOUT - HALO, Y0 = by * TOUT - HALO;
    const int c0 = X0 + 2 * l;                   // lane's first column
    const int gy0 = Y0 + 8 * w;                  // wave's first row

    const float* kB = kap + (size_t)b * IMG_K;
    const float* fB = fin + (size_t)b * IMG_K;
    const bool fast = (bx >= 1) && (bx <= 9) && (by >= 1) && (by <= 9);

    // ---- stage kappa (2 scalar streams, cols c0+1 / c0+2) and f ----
    float ko[10], kev[10];                       // rows gy0..gy0+9
    float2 fv[8];                                // f at cols (c0, c0+1), rows gy0+1..+8
    if (fast) {                                  // all accesses in-bounds
        const float* kp = kB + (size_t)gy0 * G + (c0 + 1);
        #pragma unroll
        for (int i = 0; i < 10; ++i) {
            ko[i]  = kp[(size_t)i * G];
            kev[i] = kp[(size_t)i * G + 1];
        }
        const float* fp = fB + (size_t)(gy0 + 1) * G + c0;
        #pragma unroll
        for (int r = 0; r < 8; ++r) fv[r] = *(const float2*)(fp + (size_t)r * G);
    } else {
        #pragma unroll
        for (int i = 0; i < 10; ++i) {
            const int ry = gy0 + i;
            const bool rv = (unsigned)ry < (unsigned)G;
            ko[i]  = (rv && (unsigned)(c0 + 1) < (unsigned)G) ? kB[(size_t)ry * G + (c0 + 1)] : 0.0f;
            kev[i] = (rv && (unsigned)(c0 + 2) < (unsigned)G) ? kB[(size_t)ry * G + (c0 + 2)] : 0.0f;
        }
        #pragma unroll
        for (int r = 0; r < 8; ++r) {
            const int ry = gy0 + 1 + r;
            const bool rv = (unsigned)ry < (unsigned)G;
            const float a = (rv && (unsigned)c0       < (unsigned)G) ? fB[(size_t)ry * G + c0]     : 0.0f;
            const float q = (rv && (unsigned)(c0 + 1) < (unsigned)G) ? fB[(size_t)ry * G + c0 + 1] : 0.0f;
            fv[r] = make_float2(a, q);
        }
    }

    // ---- iteration-invariant weights (explicit wE; OOB points -> all-zero) ----
    float2 wN[8], wS[8], wW[8], wE[8], Fc[8];
    #pragma unroll
    for (int r = 0; r < 8; ++r) {
        const float kn0 = ko[r],     kn1 = kev[r];
        const float kc0 = ko[r + 1], kc1 = kev[r + 1];
        const float ks0 = ko[r + 2], ks1 = kev[r + 2];
        const float kw0 = lane_shr1(kev[r + 1]);   // prev lane's c0+2 == c0 (lane0: garbage col0)
        const float kw1 = kc0;
        const float ke0 = kc1;
        const float ke1 = lane_shl1(ko[r + 1]);    // next lane's c0+1 == c0+3 (lane63: garbage col127)
        const float inv0 = frcp(2.0f * kc0 + 0.5f * (kn0 + ks0 + kw0 + ke0));
        const float inv1 = frcp(2.0f * kc1 + 0.5f * (kn1 + ks1 + kw1 + ke1));
        const float fc0 = fv[r].y;                 // f[gy+1, c0+1]
        const float fc1 = lane_shl1(fv[r].x);      // f[gy+1, c0+2] (lane63: garbage col127)
        bool d0 = true, d1 = true;
        if (!fast) {
            const int gy = gy0 + r;
            const bool rv = (unsigned)gy < (unsigned)Ni;
            d0 = rv && (unsigned)c0       < (unsigned)Ni;
            d1 = rv && (unsigned)(c0 + 1) < (unsigned)Ni;
        }
        wN[r] = make_float2(d0 ? 0.5f * (kc0 + kn0) * inv0 : 0.0f,
                            d1 ? 0.5f * (kc1 + kn1) * inv1 : 0.0f);
        wS[r] = make_float2(d0 ? 0.5f * (kc0 + ks0) * inv0 : 0.0f,
                            d1 ? 0.5f * (kc1 + ks1) * inv1 : 0.0f);
        wW[r] = make_float2(d0 ? 0.5f * (kc0 + kw0) * inv0 : 0.0f,
                            d1 ? 0.5f * (kc1 + kw1) * inv1 : 0.0f);
        wE[r] = make_float2(d0 ? 0.5f * (kc0 + ke0) * inv0 : 0.0f,
                            d1 ? 0.5f * (kc1 + ke1) * inv1 : 0.0f);
        Fc[r] = make_float2(d0 ? fc0 * H2 * inv0 : 0.0f,
                            d1 ? fc1 * H2 * inv1 : 0.0f);
    }

    // ---- u patch (loaded after weights so ko/kev/fv are dead -> VGPR peak) ----
    float2 u[8];
    if (fast) {
        const float* uS = pre + (size_t)b * IMG_P + (size_t)gy0 * Ni + c0;
        #pragma unroll
        for (int r = 0; r < 8; ++r) u[r] = *(const float2*)(uS + (size_t)r * Ni);
    } else {
        const float* uS = pre + (size_t)b * IMG_P;
        #pragma unroll
        for (int r = 0; r < 8; ++r) {
            const int gy = gy0 + r;
            const bool rv = (unsigned)gy < (unsigned)Ni;
            const float a = (rv && (unsigned)c0       < (unsigned)Ni) ? uS[(size_t)gy * Ni + c0]     : 0.0f;
            const float q = (rv && (unsigned)(c0 + 1) < (unsigned)Ni) ? uS[(size_t)gy * Ni + c0 + 1] : 0.0f;
            u[r] = make_float2(a, q);
        }
    }

    // ---- 16 steps; N/S in registers, W/E via DPP, strip edges via dbuf LDS ----
    const int iN = (w > 0)  ? tid - 64 : tid;     // wave w-1's bottom row (clamp: halo-safe)
    const int iS = (w < 15) ? tid + 64 : tid;     // wave w+1's top row
    #pragma unroll
    for (int t = 0; t < 16; ++t) {
        float2* top = ex[t & 1][0];
        float2* bot = ex[t & 1][1];
        top[tid] = u[0];
        bot[tid] = u[7];
        __syncthreads();
        const float2 hN = bot[iN];
        const float2 hS = top[iS];
        float2 pn = hN;
        #pragma unroll
        for (int r = 0; r < 8; ++r) {
            const float2 s = (r < 7) ? u[r + 1] : hS;   // old value (not yet overwritten)
            const float o0 = u[r].x, o1 = u[r].y;
            const float uW = lane_shr1(o1);             // prev lane's col1 = W of col0
            const float uE = lane_shl1(o0);             // next lane's col0 = E of col1
            const float v0 = fmaf(wN[r].x, pn.x,
                             fmaf(wS[r].x, s.x,
                             fmaf(wW[r].x, uW,
                             fmaf(wE[r].x, o1, Fc[r].x))));
            const float v1 = fmaf(wN[r].y, pn.y,
                             fmaf(wS[r].y, s.y,
                             fmaf(wW[r].y, o0,
                             fmaf(wE[r].y, uE, Fc[r].y))));
            pn = make_float2(o0, o1);
            u[r] = make_float2(v0, v1);
        }
    }

    // ---- store valid region rel [16,112)^2: waves 2..13, lanes 8..55 ----
    if (w >= 2 && w < 14 && l >= 8 && l < 56) {
        float* oB = out + (size_t)b * IMG_P;
        if (fast) {
            #pragma unroll
            for (int r = 0; r < 8; ++r)
                *(float2*)(oB + (size_t)(gy0 + r) * Ni + c0) = u[r];
        } else {
            #pragma unroll
            for (int r = 0; r < 8; ++r) {
                const int gy = gy0 + r;
                if ((unsigned)gy < (unsigned)Ni) {
                    if ((unsigned)c0       < (unsigned)Ni) oB[(size_t)gy * Ni + c0]     = u[r].x;
                    if ((unsigned)(c0 + 1) < (unsigned)Ni) oB[(size_t)gy * Ni + c0 + 1] = u[r].y;
                }
            }
        }
    }
}

extern "C" void kernel_launch(void* const* d_in, const int* in_sizes, int n_in,
                              void* d_out, int out_size, void* d_ws, size_t ws_size,
                              hipStream_t stream)
{
    const float* pre = (const float*)d_in[0];
    const float* f   = (const float*)d_in[1];
    const float* kap = (const float*)d_in[2];
    float* out = (float*)d_out;
    (void)d_ws; (void)ws_size;                   // no intermediate buffer needed

    dim3 blk(1024, 1, 1);
    dim3 grd((Ni + TOUT - 1) / TOUT, (Ni + TOUT - 1) / TOUT, 8);   // 11 x 11 x 8

    jac_fused16<<<grd, blk, 0, stream>>>(pre, out, kap, f);
}